// Round 1
// baseline (23979.950 us; speedup 1.0000x reference)
//
#include <hip/hip_runtime.h>
#include <math.h>

#define B_ 16
#define S_ 512
#define FRAME_ 438
#define DM_ 800
#define H_ 8
#define DH_ 100
#define FFN_ 1024
#define HID_ 1024
#define POSE_ 274
#define WIN_ 100
#define G4_ 4096     // 4*HID
#define KCAT_ 1824   // HID + DM

// ---------------------------------------------------------------------------
// Generic fp32 tiled GEMM: C[M,N] = A[M,K]@B[K,N] (+bias[N]) (+res[M,N])
// (+pos_table[posidx[m],:]) (optional relu). 64x64 tile, 256 thr, 4x4/thread.
// ---------------------------------------------------------------------------
__global__ __launch_bounds__(256) void gemm_f32(
    const float* __restrict__ A, const float* __restrict__ Bm,
    float* __restrict__ C, int M, int N, int K,
    const float* __restrict__ bias, const float* __restrict__ res,
    const int* __restrict__ posidx, const float* __restrict__ postab,
    int relu)
{
    __shared__ float As[16][65];
    __shared__ float Bs[16][65];
    int m0 = blockIdx.x * 64, n0 = blockIdx.y * 64;
    int tid = threadIdx.x;
    int ty = tid >> 4, tx = tid & 15;
    float acc[4][4];
#pragma unroll
    for (int i = 0; i < 4; ++i)
#pragma unroll
        for (int j = 0; j < 4; ++j) acc[i][j] = 0.f;

    for (int k0 = 0; k0 < K; k0 += 16) {
        { // A tile -> As[k][m]
            int mi = tid >> 2, kb = (tid & 3) * 4;
            int m = m0 + mi;
#pragma unroll
            for (int i = 0; i < 4; ++i) {
                int k = k0 + kb + i;
                As[kb + i][mi] = (m < M && k < K) ? A[(long)m * K + k] : 0.f;
            }
        }
        { // B tile -> Bs[k][n]
            int ki = tid >> 4, nb = (tid & 15) * 4;
            int k = k0 + ki;
#pragma unroll
            for (int i = 0; i < 4; ++i) {
                int n = n0 + nb + i;
                Bs[ki][nb + i] = (k < K && n < N) ? Bm[(long)k * N + n] : 0.f;
            }
        }
        __syncthreads();
#pragma unroll
        for (int kk = 0; kk < 16; ++kk) {
            float a[4], b[4];
#pragma unroll
            for (int i = 0; i < 4; ++i) a[i] = As[kk][ty * 4 + i];
#pragma unroll
            for (int j = 0; j < 4; ++j) b[j] = Bs[kk][tx * 4 + j];
#pragma unroll
            for (int i = 0; i < 4; ++i)
#pragma unroll
                for (int j = 0; j < 4; ++j) acc[i][j] += a[i] * b[j];
        }
        __syncthreads();
    }
#pragma unroll
    for (int i = 0; i < 4; ++i) {
        int m = m0 + ty * 4 + i;
        if (m >= M) continue;
#pragma unroll
        for (int j = 0; j < 4; ++j) {
            int n = n0 + tx * 4 + j;
            if (n >= N) continue;
            float v = acc[i][j];
            if (bias) v += bias[n];
            if (res) v += res[(long)m * N + n];
            if (posidx) v += postab[(long)posidx[m] * N + n];
            if (relu) v = fmaxf(v, 0.f);
            C[(long)m * N + n] = v;
        }
    }
}

// ---------------------------------------------------------------------------
// LayerNorm over last dim N (=800), one block per row.
// ---------------------------------------------------------------------------
__global__ __launch_bounds__(256) void ln_f32(
    const float* __restrict__ X, float* __restrict__ Y,
    const float* __restrict__ g, const float* __restrict__ b, int N)
{
    int m = blockIdx.x;
    const float* x = X + (long)m * N;
    __shared__ float red[256];
    int tid = threadIdx.x;
    float s = 0.f;
    for (int i = tid; i < N; i += 256) s += x[i];
    red[tid] = s; __syncthreads();
    for (int o = 128; o > 0; o >>= 1) { if (tid < o) red[tid] += red[tid + o]; __syncthreads(); }
    float mean = red[0] / N;
    __syncthreads();
    float v = 0.f;
    for (int i = tid; i < N; i += 256) { float d = x[i] - mean; v += d * d; }
    red[tid] = v; __syncthreads();
    for (int o = 128; o > 0; o >>= 1) { if (tid < o) red[tid] += red[tid + o]; __syncthreads(); }
    float rs = rsqrtf(red[0] / N + 1e-6f);
    for (int i = tid; i < N; i += 256)
        Y[(long)m * N + i] = (x[i] - mean) * rs * g[i] + b[i];
}

// ---------------------------------------------------------------------------
// Fused banded attention: per block = (b, h, q-tile of 4).
// scores -> softmax (window 201) -> P@V, never materializing SxS.
// ---------------------------------------------------------------------------
__global__ __launch_bounds__(256) void attn_f32(
    const float* __restrict__ Q, const float* __restrict__ K,
    const float* __restrict__ V, float* __restrict__ O)
{
    int blk = blockIdx.x;
    int qt = blk & 127; int bh = blk >> 7;
    int h = bh & 7; int b = bh >> 3;
    int q0 = qt * 4;
    int tid = threadIdx.x;

    __shared__ float qv[4][DH_];
    __shared__ float sc[4][208];
    __shared__ float red[256];
    __shared__ float inv_den[4];

    for (int i = tid; i < 4 * DH_; i += 256) {
        int qi = i / DH_, d = i - qi * DH_;
        qv[qi][d] = Q[(long)(b * S_ + q0 + qi) * DM_ + h * DH_ + d];
    }
    __syncthreads();

    int w = tid;
    int k = q0 - WIN_ + w;
    bool kvalid = (w < 204) && (k >= 0) && (k < S_);
    float dots[4] = {0.f, 0.f, 0.f, 0.f};
    if (kvalid) {
        const float* krow = K + (long)(b * S_ + k) * DM_ + h * DH_;
        for (int d = 0; d < DH_; ++d) {
            float kvv = krow[d];
#pragma unroll
            for (int qi = 0; qi < 4; ++qi) dots[qi] += qv[qi][d] * kvv;
        }
    }
#pragma unroll
    for (int qi = 0; qi < 4; ++qi) {
        int wq = w - qi;
        if (w < 204 && wq >= 0 && wq < 201)
            sc[qi][wq] = kvalid ? dots[qi] * 0.1f : -1e30f;
    }
    __syncthreads();

    for (int qi = 0; qi < 4; ++qi) {
        float vmax = (tid < 201) ? sc[qi][tid] : -1e30f;
        red[tid] = vmax; __syncthreads();
        for (int o = 128; o > 0; o >>= 1) { if (tid < o) red[tid] = fmaxf(red[tid], red[tid + o]); __syncthreads(); }
        float mx = red[0];
        __syncthreads();
        float e = 0.f;
        if (tid < 201) { e = __expf(sc[qi][tid] - mx); sc[qi][tid] = e; }
        red[tid] = e; __syncthreads();
        for (int o = 128; o > 0; o >>= 1) { if (tid < o) red[tid] += red[tid + o]; __syncthreads(); }
        if (tid == 0) inv_den[qi] = 1.f / red[0];
        __syncthreads();
    }

    if (tid < DH_) {
        int d = tid;
        float o_[4] = {0.f, 0.f, 0.f, 0.f};
        for (int w2 = 0; w2 < 204; ++w2) {
            int k2 = q0 - WIN_ + w2;
            if (k2 < 0 || k2 >= S_) continue;
            float vv = V[(long)(b * S_ + k2) * DM_ + h * DH_ + d];
#pragma unroll
            for (int qi = 0; qi < 4; ++qi) {
                int wq = w2 - qi;
                if (wq >= 0 && wq < 201) o_[qi] += sc[qi][wq] * vv;
            }
        }
#pragma unroll
        for (int qi = 0; qi < 4; ++qi)
            O[(long)(b * S_ + q0 + qi) * DM_ + h * DH_ + d] = o_[qi] * inv_den[qi];
    }
}

// g3[j] = out_b @ Wx
__global__ __launch_bounds__(256) void g3_kernel(
    const float* __restrict__ outb, const float* __restrict__ Wx, float* __restrict__ g3)
{
    int j = blockIdx.x * 256 + threadIdx.x;
    if (j >= G4_) return;
    float s = 0.f;
    for (int p = 0; p < POSE_; ++p) s += outb[p] * Wx[(long)p * G4_ + j];
    g3[j] = s;
}

__global__ __launch_bounds__(256) void init_state(
    const float* __restrict__ vh, const float* __restrict__ vc,
    float* __restrict__ h0, float* __restrict__ c)
{
    int i = blockIdx.x * 256 + threadIdx.x;
    if (i < B_ * HID_) { h0[i] = vh[i]; c[i] = vc[i]; }
}

__global__ __launch_bounds__(256) void enc_copy(
    const float* __restrict__ enc, float* __restrict__ acat)
{
    int i = blockIdx.x * 256 + threadIdx.x;
    if (i >= B_ * S_ * DM_) return;
    int m = i / DM_, d = i - m * DM_;
    acat[(long)m * KCAT_ + HID_ + d] = enc[i];
}

// ---------------------------------------------------------------------------
// One LSTM step.  gates(16 x 4096) = h @ Wh_sel + x @ Wx_sel (+biases);
// output-feedback folded into Weff_false/G2/g3 so one kernel per step.
// Grid 512 blocks x 256 thr.  Block owns 2 hidden idx (8 gate cols), all 16 b.
// LDS panel (512 k-rows x 16 b, transposed) ~50 KB.
// ---------------------------------------------------------------------------
__global__ __launch_bounds__(256) void lstm_step(
    int t,
    const float* __restrict__ hread, float* __restrict__ hwrite, float* __restrict__ cbuf,
    const float* __restrict__ ENC, const float* __restrict__ tgt, const float* __restrict__ dec0,
    const float* __restrict__ WEFF, const float* __restrict__ Wh, const float* __restrict__ Wx,
    const float* __restrict__ G2, const float* __restrict__ G3v, const float* __restrict__ lstm_b,
    const int* __restrict__ epoch, float* __restrict__ ACAT)
{
    // lds: [0,8192) panel (512 rows x 16 b) | [8192,..) partials | gst
    __shared__ float lds[8192 + 4240 + 128];
    const int PART = 8192, GST = 8192 + 4240;
    int tid = threadIdx.x;

    int p = (int)((double)epoch[0] * 0.01);   // match python int(epoch*LAMB)
    int per = p + 10;
    bool msk = (t % per) >= p;

    const float* WHsel = msk ? Wh : (t == 0 ? Wh : WEFF);
    const float* WXsel = (msk || t == 0) ? Wx : G2;
    int KX = (msk || t == 0) ? POSE_ : DM_;
    bool addg3 = (!msk) && (t > 0);
    int K_tot = HID_ + KX;

    int jcol = tid & 7;            // gate*2 + hh
    int kgrp = tid >> 3;           // 0..31
    int gate = jcol >> 1, hh = jcol & 1;
    int hid = blockIdx.x * 2 + hh;
    int gcol = gate * HID_ + hid;

    float acc[16];
#pragma unroll
    for (int i = 0; i < 16; ++i) acc[i] = 0.f;

    for (int P = 0; P < K_tot; P += 512) {
        int plen = K_tot - P; if (plen > 512) plen = 512;
        // ---- stage panel (transposed: lds[kl*16 + b]) ----
        if (P < HID_) { // h panel, float4 path (plen==512 always here)
            for (int idx = tid; idx < 2048; idx += 256) {
                int b = idx & 15, k4 = idx >> 4;
                const float4 hv = *(const float4*)(hread + b * HID_ + P + k4 * 4);
                float* dst = &lds[(k4 * 4) * 16 + b];
                dst[0] = hv.x; dst[16] = hv.y; dst[32] = hv.z; dst[48] = hv.w;
            }
        } else {        // x panel, scalar path
            int xoff = P - HID_;
            for (int idx = tid; idx < plen * 16; idx += 256) {
                int b = idx & 15, kl = idx >> 4;
                int kk = xoff + kl;
                float v;
                if (msk)          v = tgt[(long)(b * S_ + t) * POSE_ + kk];
                else if (t == 0)  v = dec0[b * POSE_ + kk];
                else              v = ENC[(long)(b * S_ + (t - 1)) * DM_ + kk];
                lds[kl * 16 + b] = v;
            }
        }
        __syncthreads();
        // ---- accumulate this panel ----
        const float* wbase = (P < HID_) ? (WHsel + (long)P * G4_)
                                        : (WXsel + (long)(P - HID_) * G4_);
        int kls = kgrp * 16;
#pragma unroll
        for (int g0 = 0; g0 < 16; g0 += 4) {
            float w[4];
#pragma unroll
            for (int u = 0; u < 4; ++u) {
                int kl = kls + g0 + u;
                w[u] = (kl < plen) ? wbase[(long)kl * G4_ + gcol] : 0.f;
            }
#pragma unroll
            for (int u = 0; u < 4; ++u) {
                int kl = kls + g0 + u;
                if (kl < plen) {
                    const float4 b0 = *(const float4*)&lds[kl * 16 + 0];
                    const float4 b1 = *(const float4*)&lds[kl * 16 + 4];
                    const float4 b2 = *(const float4*)&lds[kl * 16 + 8];
                    const float4 b3 = *(const float4*)&lds[kl * 16 + 12];
                    float wu = w[u];
                    acc[0]  += b0.x * wu; acc[1]  += b0.y * wu; acc[2]  += b0.z * wu; acc[3]  += b0.w * wu;
                    acc[4]  += b1.x * wu; acc[5]  += b1.y * wu; acc[6]  += b1.z * wu; acc[7]  += b1.w * wu;
                    acc[8]  += b2.x * wu; acc[9]  += b2.y * wu; acc[10] += b2.z * wu; acc[11] += b2.w * wu;
                    acc[12] += b3.x * wu; acc[13] += b3.y * wu; acc[14] += b3.z * wu; acc[15] += b3.w * wu;
                }
            }
        }
        __syncthreads();
    }

    // ---- write partials ----
#pragma unroll
    for (int b = 0; b < 16; ++b)
        lds[PART + (b * 33 + kgrp) * 8 + jcol] = acc[b];
    __syncthreads();

    // ---- reduce across 32 k-groups ----
    if (tid < 128) {
        int jcol2 = tid & 7, b2 = tid >> 3;
        float gv = 0.f;
#pragma unroll
        for (int kg = 0; kg < 32; ++kg)
            gv += lds[PART + (b2 * 33 + kg) * 8 + jcol2];
        int gate2 = jcol2 >> 1, hh2 = jcol2 & 1;
        int gcol2 = gate2 * HID_ + blockIdx.x * 2 + hh2;
        gv += lstm_b[gcol2];
        if (addg3) gv += G3v[gcol2];
        lds[GST + jcol2 * 16 + b2] = gv;
    }
    __syncthreads();

    // ---- elementwise LSTM update ----
    if (tid < 32) {
        int b3 = tid >> 1, hh3 = tid & 1;
        int hid3 = blockIdx.x * 2 + hh3;
        float iv = lds[GST + (0 * 2 + hh3) * 16 + b3];
        float fv = lds[GST + (1 * 2 + hh3) * 16 + b3];
        float gv = lds[GST + (2 * 2 + hh3) * 16 + b3];
        float ov = lds[GST + (3 * 2 + hh3) * 16 + b3];
        float c_old = cbuf[b3 * HID_ + hid3];
        float ig = 1.f / (1.f + __expf(-iv));
        float fg = 1.f / (1.f + __expf(-fv));
        float og = 1.f / (1.f + __expf(-ov));
        float cn = fg * c_old + ig * tanhf(gv);
        float hn = og * tanhf(cn);
        cbuf[b3 * HID_ + hid3] = cn;
        hwrite[b3 * HID_ + hid3] = hn;
        ACAT[(long)(b3 * S_ + t) * KCAT_ + hid3] = hn;
    }
}

// ---------------------------------------------------------------------------
extern "C" void kernel_launch(void* const* d_in, const int* in_sizes, int n_in,
                              void* d_out, int out_size, void* d_ws, size_t ws_size,
                              hipStream_t stream) {
    const float* src_seq  = (const float*)d_in[0];
    const int*   src_pos  = (const int*)  d_in[1];
    const float* tgt_seq  = (const float*)d_in[2];
    const float* vec_h    = (const float*)d_in[3];
    const float* vec_c    = (const float*)d_in[4];
    const float* dec0     = (const float*)d_in[5];
    const float* emb_W    = (const float*)d_in[6];
    const float* emb_b    = (const float*)d_in[7];
    const float* pos_tab  = (const float*)d_in[8];
    const float* Wq       = (const float*)d_in[9];
    const float* Wk       = (const float*)d_in[10];
    const float* Wv       = (const float*)d_in[11];
    const float* Wo       = (const float*)d_in[12];
    const float* ln1_g    = (const float*)d_in[13];
    const float* ln1_b    = (const float*)d_in[14];
    const float* ffn_W1   = (const float*)d_in[15];
    const float* ffn_b1   = (const float*)d_in[16];
    const float* ffn_W2   = (const float*)d_in[17];
    const float* ffn_b2   = (const float*)d_in[18];
    const float* ln2_g    = (const float*)d_in[19];
    const float* ln2_b    = (const float*)d_in[20];
    const float* lstm_Wx  = (const float*)d_in[21];
    const float* lstm_Wh  = (const float*)d_in[22];
    const float* lstm_b   = (const float*)d_in[23];
    const float* out_W    = (const float*)d_in[24];
    const float* out_b    = (const float*)d_in[25];
    const int*   epoch    = (const int*)  d_in[26];

    float* ws = (float*)d_ws;
    const long NX = (long)B_ * S_ * DM_;         // 6,553,600
    float* X    = ws;                            // residual stream / enc
    float* Qb   = X + NX;
    float* Kb   = Qb + NX;
    float* Vb   = Kb + NX;
    float* Ob   = Vb + NX;
    float* FFNH = Ob + NX;                       // 8,388,608
    float* WEFF = FFNH + (long)B_ * S_ * FFN_;   // 4,194,304
    float* G2   = WEFF + (long)HID_ * G4_;       // 3,276,800
    float* G3v  = G2 + (long)DM_ * G4_;          // 4096
    float* HB0  = G3v + G4_;
    float* HB1  = HB0 + B_ * HID_;
    float* CB   = HB1 + B_ * HID_;
    float* ACAT = Qb;                            // alias (Q/K/V dead after attn)

    const int M = B_ * S_; // 8192
    dim3 blk(256);

    // ---- encoder ----
    gemm_f32<<<dim3((M + 63) / 64, (DM_ + 63) / 64), blk, 0, stream>>>(
        src_seq, emb_W, X, M, DM_, FRAME_, emb_b, nullptr, src_pos, pos_tab, 0);
    gemm_f32<<<dim3((M + 63) / 64, (DM_ + 63) / 64), blk, 0, stream>>>(
        X, Wq, Qb, M, DM_, DM_, nullptr, nullptr, nullptr, nullptr, 0);
    gemm_f32<<<dim3((M + 63) / 64, (DM_ + 63) / 64), blk, 0, stream>>>(
        X, Wk, Kb, M, DM_, DM_, nullptr, nullptr, nullptr, nullptr, 0);
    gemm_f32<<<dim3((M + 63) / 64, (DM_ + 63) / 64), blk, 0, stream>>>(
        X, Wv, Vb, M, DM_, DM_, nullptr, nullptr, nullptr, nullptr, 0);
    attn_f32<<<dim3(B_ * H_ * (S_ / 4)), blk, 0, stream>>>(Qb, Kb, Vb, Ob);
    gemm_f32<<<dim3((M + 63) / 64, (DM_ + 63) / 64), blk, 0, stream>>>(
        Ob, Wo, FFNH, M, DM_, DM_, nullptr, X, nullptr, nullptr, 0);
    ln_f32<<<dim3(M), blk, 0, stream>>>(FFNH, X, ln1_g, ln1_b, DM_);
    gemm_f32<<<dim3((M + 63) / 64, (FFN_ + 63) / 64), blk, 0, stream>>>(
        X, ffn_W1, FFNH, M, FFN_, DM_, ffn_b1, nullptr, nullptr, nullptr, 1);
    gemm_f32<<<dim3((M + 63) / 64, (DM_ + 63) / 64), blk, 0, stream>>>(
        FFNH, ffn_W2, Ob, M, DM_, FFN_, ffn_b2, X, nullptr, nullptr, 0);
    ln_f32<<<dim3(M), blk, 0, stream>>>(Ob, X, ln2_g, ln2_b, DM_);   // X = enc

    // ---- decoder precompute (output-feedback folding) ----
    enc_copy<<<dim3((B_ * S_ * DM_ + 255) / 256), blk, 0, stream>>>(X, ACAT);
    gemm_f32<<<dim3((HID_ + 63) / 64, (G4_ + 63) / 64), blk, 0, stream>>>(
        out_W, lstm_Wx, WEFF, HID_, G4_, POSE_, nullptr, lstm_Wh, nullptr, nullptr, 0);
    gemm_f32<<<dim3((DM_ + 63) / 64, (G4_ + 63) / 64), blk, 0, stream>>>(
        out_W + (long)HID_ * POSE_, lstm_Wx, G2, DM_, G4_, POSE_, nullptr, nullptr, nullptr, nullptr, 0);
    g3_kernel<<<dim3(G4_ / 256), blk, 0, stream>>>(out_b, lstm_Wx, G3v);
    init_state<<<dim3((B_ * HID_ + 255) / 256), blk, 0, stream>>>(vec_h, vec_c, HB0, CB);

    // ---- sequential scan: one kernel per step ----
    for (int t = 0; t < S_; ++t) {
        const float* hr = (t & 1) ? HB1 : HB0;
        float* hw       = (t & 1) ? HB0 : HB1;
        lstm_step<<<dim3(512), blk, 0, stream>>>(
            t, hr, hw, CB, X, tgt_seq, dec0,
            WEFF, lstm_Wh, lstm_Wx, G2, G3v, lstm_b, epoch, ACAT);
    }

    // ---- final output projection: out = [H_all, enc] @ out_W + out_b ----
    gemm_f32<<<dim3((M + 63) / 64, (POSE_ + 63) / 64), blk, 0, stream>>>(
        ACAT, out_W, (float*)d_out, M, POSE_, KCAT_, out_b, nullptr, nullptr, nullptr, 0);
}

// Round 3
// 18291.620 us; speedup vs baseline: 1.3110x; 1.3110x over previous
//
#include <hip/hip_runtime.h>
#include <math.h>

#define B_ 16
#define S_ 512
#define FRAME_ 438
#define DM_ 800
#define H_ 8
#define DH_ 100
#define FFN_ 1024
#define HID_ 1024
#define POSE_ 274
#define WIN_ 100
#define G4_ 4096     // 4*HID
#define KPA_ 1536    // padded K for WT_A ([Wh;Wx], K=1298)
#define KPB_ 2048    // padded K for WT_B ([WEFF;G2], K=1824)

// ---------------------------------------------------------------------------
// gemm128: fp32, 128x128 tile, 256 thr, 8x8 micro (split 4+4, conflict-free
// LDS). C = A@B (+bias[N]) (+res[M,N]) (+pos_table[posidx[m]]) (relu).
// ---------------------------------------------------------------------------
__global__ __launch_bounds__(256) void gemm128(
    const float* __restrict__ A, const float* __restrict__ Bm,
    float* __restrict__ C, int M, int N, int K,
    const float* __restrict__ bias, const float* __restrict__ res,
    const int* __restrict__ posidx, const float* __restrict__ postab,
    int relu)
{
    __shared__ float As[16 * 132];
    __shared__ float Bs[16 * 132];
    int m0 = blockIdx.x * 128, n0 = blockIdx.y * 128;
    int tid = threadIdx.x;
    int tx = tid & 15, ty = tid >> 4;
    float acc[8][8];
#pragma unroll
    for (int i = 0; i < 8; ++i)
#pragma unroll
        for (int j = 0; j < 8; ++j) acc[i][j] = 0.f;

    for (int k0 = 0; k0 < K; k0 += 16) {
#pragma unroll
        for (int i = 0; i < 8; ++i) {             // A: 128 m x 16 k
            int idx = i * 256 + tid;
            int m = idx >> 4, kl = idx & 15;
            int r = m0 + m, k = k0 + kl;
            As[kl * 132 + m] = (r < M && k < K) ? A[(long)r * K + k] : 0.f;
        }
#pragma unroll
        for (int i = 0; i < 8; ++i) {             // B: 16 k x 128 n
            int idx = i * 256 + tid;
            int n = idx & 127, k = idx >> 7;
            int kk = k0 + k, nn = n0 + n;
            Bs[k * 132 + n] = (kk < K && nn < N) ? Bm[(long)kk * N + nn] : 0.f;
        }
        __syncthreads();
#pragma unroll
        for (int kk = 0; kk < 16; ++kk) {
            float4 a0 = *(const float4*)&As[kk * 132 + ty * 4];
            float4 a1 = *(const float4*)&As[kk * 132 + 64 + ty * 4];
            float4 b0 = *(const float4*)&Bs[kk * 132 + tx * 4];
            float4 b1 = *(const float4*)&Bs[kk * 132 + 64 + tx * 4];
            float a[8] = {a0.x, a0.y, a0.z, a0.w, a1.x, a1.y, a1.z, a1.w};
            float b[8] = {b0.x, b0.y, b0.z, b0.w, b1.x, b1.y, b1.z, b1.w};
#pragma unroll
            for (int i = 0; i < 8; ++i)
#pragma unroll
                for (int j = 0; j < 8; ++j) acc[i][j] += a[i] * b[j];
        }
        __syncthreads();
    }
#pragma unroll
    for (int i = 0; i < 8; ++i) {
        int m = m0 + ((i < 4) ? (ty * 4 + i) : (64 + ty * 4 + i - 4));
        if (m >= M) continue;
#pragma unroll
        for (int j = 0; j < 8; ++j) {
            int n = n0 + ((j < 4) ? (tx * 4 + j) : (64 + tx * 4 + j - 4));
            if (n >= N) continue;
            float v = acc[i][j];
            if (bias) v += bias[n];
            if (res) v += res[(long)m * N + n];
            if (posidx) v += postab[(long)posidx[m] * N + n];
            if (relu) v = fmaxf(v, 0.f);
            C[(long)m * N + n] = v;
        }
    }
}

// ---------------------------------------------------------------------------
// LayerNorm over last dim N (=800), one block per row.
// ---------------------------------------------------------------------------
__global__ __launch_bounds__(256) void ln_f32(
    const float* __restrict__ X, float* __restrict__ Y,
    const float* __restrict__ g, const float* __restrict__ b, int N)
{
    int m = blockIdx.x;
    const float* x = X + (long)m * N;
    __shared__ float red[256];
    int tid = threadIdx.x;
    float s = 0.f;
    for (int i = tid; i < N; i += 256) s += x[i];
    red[tid] = s; __syncthreads();
    for (int o = 128; o > 0; o >>= 1) { if (tid < o) red[tid] += red[tid + o]; __syncthreads(); }
    float mean = red[0] / N;
    __syncthreads();
    float v = 0.f;
    for (int i = tid; i < N; i += 256) { float d = x[i] - mean; v += d * d; }
    red[tid] = v; __syncthreads();
    for (int o = 128; o > 0; o >>= 1) { if (tid < o) red[tid] += red[tid + o]; __syncthreads(); }
    float rs = rsqrtf(red[0] / N + 1e-6f);
    for (int i = tid; i < N; i += 256)
        Y[(long)m * N + i] = (x[i] - mean) * rs * g[i] + b[i];
}

// ---------------------------------------------------------------------------
// Fused banded attention (verified round 1).
// ---------------------------------------------------------------------------
__global__ __launch_bounds__(256) void attn_f32(
    const float* __restrict__ Q, const float* __restrict__ K,
    const float* __restrict__ V, float* __restrict__ O)
{
    int blk = blockIdx.x;
    int qt = blk & 127; int bh = blk >> 7;
    int h = bh & 7; int b = bh >> 3;
    int q0 = qt * 4;
    int tid = threadIdx.x;

    __shared__ float qv[4][DH_];
    __shared__ float sc[4][208];
    __shared__ float red[256];
    __shared__ float inv_den[4];

    for (int i = tid; i < 4 * DH_; i += 256) {
        int qi = i / DH_, d = i - qi * DH_;
        qv[qi][d] = Q[(long)(b * S_ + q0 + qi) * DM_ + h * DH_ + d];
    }
    __syncthreads();

    int w = tid;
    int k = q0 - WIN_ + w;
    bool kvalid = (w < 204) && (k >= 0) && (k < S_);
    float dots[4] = {0.f, 0.f, 0.f, 0.f};
    if (kvalid) {
        const float* krow = K + (long)(b * S_ + k) * DM_ + h * DH_;
        for (int d = 0; d < DH_; ++d) {
            float kvv = krow[d];
#pragma unroll
            for (int qi = 0; qi < 4; ++qi) dots[qi] += qv[qi][d] * kvv;
        }
    }
#pragma unroll
    for (int qi = 0; qi < 4; ++qi) {
        int wq = w - qi;
        if (w < 204 && wq >= 0 && wq < 201)
            sc[qi][wq] = kvalid ? dots[qi] * 0.1f : -1e30f;
    }
    __syncthreads();

    for (int qi = 0; qi < 4; ++qi) {
        float vmax = (tid < 201) ? sc[qi][tid] : -1e30f;
        red[tid] = vmax; __syncthreads();
        for (int o = 128; o > 0; o >>= 1) { if (tid < o) red[tid] = fmaxf(red[tid], red[tid + o]); __syncthreads(); }
        float mx = red[0];
        __syncthreads();
        float e = 0.f;
        if (tid < 201) { e = __expf(sc[qi][tid] - mx); sc[qi][tid] = e; }
        red[tid] = e; __syncthreads();
        for (int o = 128; o > 0; o >>= 1) { if (tid < o) red[tid] += red[tid + o]; __syncthreads(); }
        if (tid == 0) inv_den[qi] = 1.f / red[0];
        __syncthreads();
    }

    if (tid < DH_) {
        int d = tid;
        float o_[4] = {0.f, 0.f, 0.f, 0.f};
        for (int w2 = 0; w2 < 204; ++w2) {
            int k2 = q0 - WIN_ + w2;
            if (k2 < 0 || k2 >= S_) continue;
            float vv = V[(long)(b * S_ + k2) * DM_ + h * DH_ + d];
#pragma unroll
            for (int qi = 0; qi < 4; ++qi) {
                int wq = w2 - qi;
                if (wq >= 0 && wq < 201) o_[qi] += sc[qi][wq] * vv;
            }
        }
#pragma unroll
        for (int qi = 0; qi < 4; ++qi)
            O[(long)(b * S_ + q0 + qi) * DM_ + h * DH_ + d] = o_[qi] * inv_den[qi];
    }
}

// g3[j] = out_b @ Wx
__global__ __launch_bounds__(256) void g3_kernel(
    const float* __restrict__ outb, const float* __restrict__ Wx, float* __restrict__ g3)
{
    int j = blockIdx.x * 256 + threadIdx.x;
    if (j >= G4_) return;
    float s = 0.f;
    for (int p = 0; p < POSE_; ++p) s += outb[p] * Wx[(long)p * G4_ + j];
    g3[j] = s;
}

__global__ __launch_bounds__(256) void init_state(
    const float* __restrict__ vh, const float* __restrict__ vc,
    float* __restrict__ h0, float* __restrict__ c)
{
    int i = blockIdx.x * 256 + threadIdx.x;
    if (i < B_ * HID_) { h0[i] = vh[i]; c[i] = vc[i]; }
}

// ---------------------------------------------------------------------------
// tr_cat: WT[c][k] = (k<K1 ? in1[k][c] : k<K1+K2 ? in2[k-K1][c] : 0)
// in1/in2 row-major with 4096 cols; WT row stride KP. grid (KP/64, 64).
// ---------------------------------------------------------------------------
__global__ __launch_bounds__(256) void tr_cat(
    const float* __restrict__ in1, const float* __restrict__ in2,
    float* __restrict__ WT, int K1, int K2, int KP)
{
    __shared__ float tile[64][65];
    int k0 = blockIdx.x * 64, c0 = blockIdx.y * 64;
    int tid = threadIdx.x;
    int cl = tid & 63, kr = tid >> 6;
#pragma unroll
    for (int i = 0; i < 16; ++i) {
        int kl = i * 4 + kr;
        int k = k0 + kl, c = c0 + cl;
        float v = 0.f;
        if (k < K1) v = in1[(long)k * G4_ + c];
        else if (k < K1 + K2) v = in2[(long)(k - K1) * G4_ + c];
        tile[kl][cl] = v;
    }
    __syncthreads();
    int kl2 = tid & 63, cr = tid >> 6;
#pragma unroll
    for (int i = 0; i < 16; ++i) {
        int ci = i * 4 + cr;
        WT[(long)(c0 + ci) * KP + k0 + kl2] = tile[kl2][ci];
    }
}

// ---------------------------------------------------------------------------
// lstm_step3: gates(16 x 4096) = [h; x] @ W_sel  (K folded; no XG buffer).
// grid 512 blocks (2 hid x 4 gates) x 256 thr. Panels of 256 k staged to
// LDS stride 17 (2-way banks = free). Weights pre-transposed + zero-padded
// so the FMA loop has no guards. LDS ~27 KB.
// ---------------------------------------------------------------------------
__global__ __launch_bounds__(256) void lstm_step3(
    int t, const float* __restrict__ hread, float* __restrict__ hwrite,
    float* __restrict__ cbuf,
    const float* __restrict__ WT_A, const float* __restrict__ WT_B,
    const float* __restrict__ g3, const float* __restrict__ lstm_b,
    const int* __restrict__ epoch,
    const float* __restrict__ tgt, const float* __restrict__ dec0,
    const float* __restrict__ ENC, float* __restrict__ Hall)
{
    __shared__ float pan[256 * 17];
    __shared__ float red[2304];
    __shared__ float gst[128];
    int tid = threadIdx.x;
    int p = (int)((double)epoch[0] * 0.01);   // match python int(epoch*LAMB)
    int per = p + 10;
    bool msk = (t % per) >= p;
    bool useA = msk || (t == 0);
    const float* WT = useA ? WT_A : WT_B;
    const int KP = useA ? KPA_ : KPB_;
    const int KX = useA ? POSE_ : DM_;
    int hid0 = blockIdx.x * 2;
    int kq = tid >> 4, b = tid & 15;

    const float* wrow[8];
#pragma unroll
    for (int c = 0; c < 8; ++c)
        wrow[c] = WT + (long)((c >> 1) * 1024 + hid0 + (c & 1)) * KP;

    float acc[8] = {0.f, 0.f, 0.f, 0.f, 0.f, 0.f, 0.f, 0.f};

    for (int P = 0; P < KP; P += 256) {
        // ---- stage [h;x] panel: pan[kl*17 + b], kl = tid (coalesced k) ----
        if (P < 1024) {
#pragma unroll
            for (int bb = 0; bb < 16; ++bb)
                pan[tid * 17 + bb] = hread[bb * 1024 + P + tid];
        } else {
            int kx = P - 1024 + tid;
#pragma unroll
            for (int bb = 0; bb < 16; ++bb) {
                float v = 0.f;
                if (kx < KX) {
                    if (useA) v = msk ? tgt[((long)bb * S_ + t) * POSE_ + kx]
                                      : dec0[bb * POSE_ + kx];
                    else      v = ENC[((long)bb * S_ + (t - 1)) * DM_ + kx];
                }
                pan[tid * 17 + bb] = v;
            }
        }
        __syncthreads();
        int kb = P + kq * 16;
#pragma unroll
        for (int j4 = 0; j4 < 4; ++j4) {
            float4 w[8];
#pragma unroll
            for (int c = 0; c < 8; ++c)
                w[c] = *(const float4*)(wrow[c] + kb + j4 * 4);
            float h0 = pan[(kq * 16 + j4 * 4 + 0) * 17 + b];
            float h1 = pan[(kq * 16 + j4 * 4 + 1) * 17 + b];
            float h2 = pan[(kq * 16 + j4 * 4 + 2) * 17 + b];
            float h3 = pan[(kq * 16 + j4 * 4 + 3) * 17 + b];
#pragma unroll
            for (int c = 0; c < 8; ++c)
                acc[c] += w[c].x * h0 + w[c].y * h1 + w[c].z * h2 + w[c].w * h3;
        }
        __syncthreads();
    }

#pragma unroll
    for (int c = 0; c < 8; ++c) red[(b * 16 + kq) * 9 + c] = acc[c];
    __syncthreads();

    if (tid < 128) {
        int ob = tid >> 3, oc = tid & 7;
        float s = 0.f;
#pragma unroll
        for (int q = 0; q < 16; ++q) s += red[(ob * 16 + q) * 9 + oc];
        int gcol = (oc >> 1) * 1024 + hid0 + (oc & 1);
        s += lstm_b[gcol];
        if (!useA) s += g3[gcol];
        gst[oc * 16 + ob] = s;
    }
    __syncthreads();

    if (tid < 32) {
        int b3 = tid >> 1, hh = tid & 1;
        int hid = hid0 + hh;
        float iv = gst[(0 * 2 + hh) * 16 + b3];
        float fv = gst[(1 * 2 + hh) * 16 + b3];
        float gv = gst[(2 * 2 + hh) * 16 + b3];
        float ov = gst[(3 * 2 + hh) * 16 + b3];
        float c_old = cbuf[b3 * HID_ + hid];
        float ig = 1.f / (1.f + __expf(-iv));
        float fg = 1.f / (1.f + __expf(-fv));
        float og = 1.f / (1.f + __expf(-ov));
        float cn = fg * c_old + ig * tanhf(gv);
        float hn = og * tanhf(cn);
        cbuf[b3 * HID_ + hid] = cn;
        hwrite[b3 * HID_ + hid] = hn;
        Hall[((long)b3 * S_ + t) * HID_ + hid] = hn;
    }
}

// ---------------------------------------------------------------------------
extern "C" void kernel_launch(void* const* d_in, const int* in_sizes, int n_in,
                              void* d_out, int out_size, void* d_ws, size_t ws_size,
                              hipStream_t stream) {
    const float* src_seq  = (const float*)d_in[0];
    const int*   src_pos  = (const int*)  d_in[1];
    const float* tgt_seq  = (const float*)d_in[2];
    const float* vec_h    = (const float*)d_in[3];
    const float* vec_c    = (const float*)d_in[4];
    const float* dec0     = (const float*)d_in[5];
    const float* emb_W    = (const float*)d_in[6];
    const float* emb_b    = (const float*)d_in[7];
    const float* pos_tab  = (const float*)d_in[8];
    const float* Wq       = (const float*)d_in[9];
    const float* Wk       = (const float*)d_in[10];
    const float* Wv       = (const float*)d_in[11];
    const float* Wo       = (const float*)d_in[12];
    const float* ln1_g    = (const float*)d_in[13];
    const float* ln1_b    = (const float*)d_in[14];
    const float* ffn_W1   = (const float*)d_in[15];
    const float* ffn_b1   = (const float*)d_in[16];
    const float* ffn_W2   = (const float*)d_in[17];
    const float* ffn_b2   = (const float*)d_in[18];
    const float* ln2_g    = (const float*)d_in[19];
    const float* ln2_b    = (const float*)d_in[20];
    const float* lstm_Wx  = (const float*)d_in[21];
    const float* lstm_Wh  = (const float*)d_in[22];
    const float* lstm_b   = (const float*)d_in[23];
    const float* out_W    = (const float*)d_in[24];
    const float* out_b    = (const float*)d_in[25];
    const int*   epoch    = (const int*)  d_in[26];

    // ---- workspace layout (total 41,209,856 floats = 164.8 MB) ----
    float* ws = (float*)d_ws;
    const long NX = (long)B_ * S_ * DM_;           // 6,553,600
    float* X      = ws;                            // enc / residual [0, NX)
    float* R      = X + NX;                        // 34,603,008-float region
    // encoder phase:
    float* Qb     = R;
    float* Kb     = Qb + NX;
    float* Vb     = Kb + NX;
    float* Ob     = Vb + NX;
    float* FFNH   = Ob + NX;                       // 8,388,608
    // decoder phase (aliases into R; encoder scratch dead):
    float* WEFF_t = R;                             // 4,194,304
    float* G2     = R + 4194304;                   // 3,276,800
    float* WT_A   = R + 7471104;                   // 6,291,456 (4096 x 1536)
    float* WT_B   = R + 13762560;                  // 8,388,608 (4096 x 2048)
    float* Hall   = R + 22151168;                  // 8,388,608 (B*S x 1024)
    float* T1     = WEFF_t;                        // 2,244,608 (after WT_B built)
    float* TAIL   = R + 34603008;
    float* G3v    = TAIL;                          // 4096
    float* HB0    = G3v + G4_;                     // 16384
    float* HB1    = HB0 + B_ * HID_;
    float* CB     = HB1 + B_ * HID_;

    const int M = B_ * S_; // 8192
    dim3 blk(256);

    // ---- encoder ----
    gemm128<<<dim3(M / 128, (DM_ + 127) / 128), blk, 0, stream>>>(
        src_seq, emb_W, X, M, DM_, FRAME_, emb_b, nullptr, src_pos, pos_tab, 0);
    gemm128<<<dim3(M / 128, (DM_ + 127) / 128), blk, 0, stream>>>(
        X, Wq, Qb, M, DM_, DM_, nullptr, nullptr, nullptr, nullptr, 0);
    gemm128<<<dim3(M / 128, (DM_ + 127) / 128), blk, 0, stream>>>(
        X, Wk, Kb, M, DM_, DM_, nullptr, nullptr, nullptr, nullptr, 0);
    gemm128<<<dim3(M / 128, (DM_ + 127) / 128), blk, 0, stream>>>(
        X, Wv, Vb, M, DM_, DM_, nullptr, nullptr, nullptr, nullptr, 0);
    attn_f32<<<dim3(B_ * H_ * (S_ / 4)), blk, 0, stream>>>(Qb, Kb, Vb, Ob);
    gemm128<<<dim3(M / 128, (DM_ + 127) / 128), blk, 0, stream>>>(
        Ob, Wo, FFNH, M, DM_, DM_, nullptr, X, nullptr, nullptr, 0);
    ln_f32<<<dim3(M), blk, 0, stream>>>(FFNH, X, ln1_g, ln1_b, DM_);
    gemm128<<<dim3(M / 128, FFN_ / 128), blk, 0, stream>>>(
        X, ffn_W1, FFNH, M, FFN_, DM_, ffn_b1, nullptr, nullptr, nullptr, 1);
    gemm128<<<dim3(M / 128, (DM_ + 127) / 128), blk, 0, stream>>>(
        FFNH, ffn_W2, Ob, M, DM_, FFN_, ffn_b2, X, nullptr, nullptr, 0);
    ln_f32<<<dim3(M), blk, 0, stream>>>(Ob, X, ln2_g, ln2_b, DM_);   // X = enc

    // ---- decoder precompute ----
    // WEFF_t = out_W[:1024]@lstm_Wx + lstm_Wh   (1024 x 4096)
    gemm128<<<dim3(HID_ / 128, G4_ / 128), blk, 0, stream>>>(
        out_W, lstm_Wx, WEFF_t, HID_, G4_, POSE_, nullptr, lstm_Wh, nullptr, nullptr, 0);
    // G2 = out_W[1024:]@lstm_Wx   (800 x 4096)
    gemm128<<<dim3((DM_ + 127) / 128, G4_ / 128), blk, 0, stream>>>(
        out_W + (long)HID_ * POSE_, lstm_Wx, G2, DM_, G4_, POSE_,
        nullptr, nullptr, nullptr, nullptr, 0);
    // transposed, zero-padded step weights
    tr_cat<<<dim3(KPA_ / 64, G4_ / 64), blk, 0, stream>>>(
        lstm_Wh, lstm_Wx, WT_A, HID_, POSE_, KPA_);
    tr_cat<<<dim3(KPB_ / 64, G4_ / 64), blk, 0, stream>>>(
        WEFF_t, G2, WT_B, HID_, DM_, KPB_);
    g3_kernel<<<dim3(G4_ / 256), blk, 0, stream>>>(out_b, lstm_Wx, G3v);
    init_state<<<dim3((B_ * HID_ + 255) / 256), blk, 0, stream>>>(vec_h, vec_c, HB0, CB);
    // T1 = enc@out_W[1024:,:] + out_b  (aliases WEFF_t -> must follow tr_cat)
    gemm128<<<dim3(M / 128, (POSE_ + 127) / 128), blk, 0, stream>>>(
        X, out_W + (long)HID_ * POSE_, T1, M, POSE_, DM_, out_b,
        nullptr, nullptr, nullptr, 0);

    // ---- sequential scan ----
    for (int t = 0; t < S_; ++t) {
        const float* hr = (t & 1) ? HB1 : HB0;
        float* hw       = (t & 1) ? HB0 : HB1;
        lstm_step3<<<dim3(512), blk, 0, stream>>>(
            t, hr, hw, CB, WT_A, WT_B, G3v, lstm_b, epoch,
            tgt_seq, dec0, X, Hall);
    }

    // ---- final: out = Hall@out_W[:1024] + T1 ----
    gemm128<<<dim3(M / 128, (POSE_ + 127) / 128), blk, 0, stream>>>(
        Hall, out_W, (float*)d_out, M, POSE_, HID_, nullptr, T1,
        nullptr, nullptr, 0);
}